// Round 11
// baseline (220.500 us; speedup 1.0000x reference)
//
#include <hip/hip_runtime.h>

typedef unsigned short ushort_t;
typedef unsigned char uchar_t;
typedef __attribute__((ext_vector_type(8))) short bf16x8;
typedef __attribute__((ext_vector_type(4))) float f32x4;
typedef __attribute__((ext_vector_type(16))) float f32x16;
typedef __attribute__((ext_vector_type(8))) int v8i;
typedef __attribute__((ext_vector_type(4))) int v4i;

__device__ __forceinline__ unsigned short f2bf(float f) {
  union { float f; unsigned int u; } v; v.f = f;
  unsigned int r = v.u + 0x7FFFu + ((v.u >> 16) & 1u);
  return (unsigned short)(r >> 16);
}

__device__ __forceinline__ float bf2f(unsigned short u) {
  union { unsigned int i; float f; } v; v.i = ((unsigned int)u) << 16;
  return v.f;
}

__device__ __forceinline__ void gl_lds16(const void* gsrc, void* ldst) {
  __builtin_amdgcn_global_load_lds(
      (const __attribute__((address_space(1))) void*)gsrc,
      (__attribute__((address_space(3))) void*)ldst, 16, 0, 0);
}

__device__ __forceinline__ unsigned lds_addr(void* p) {
  return (unsigned)(uintptr_t)(__attribute__((address_space(3))) void*)p;
}

__device__ __forceinline__ int frag_idx(int oc, int ci) {
  return (((oc>>4)*8 + (ci>>5))<<9) + ((((ci>>3)&3)*16 + (oc&15))<<3) + (ci&7);
}

// ---------------------------------------------------------------------------
// K1: fragment-major bf16 weight bank Wf[640][256] (Q=wq, K=wk, V=w128@wv)
//     + bias_all[640].  Blocks 0..511: copy/cast QK.  512..639: V-fold, 1 oc
//     per block.
// ---------------------------------------------------------------------------
__global__ __launch_bounds__(256) void k1_weights(
    const float* __restrict__ wq, const float* __restrict__ bq,
    const float* __restrict__ wk, const float* __restrict__ bk,
    const float* __restrict__ wv, const float* __restrict__ bv,
    const float* __restrict__ w128,
    ushort_t* __restrict__ Wf, float* __restrict__ bias_all)
{
  const int ci = threadIdx.x;
  const int oc = blockIdx.x;
  if (oc < 512) {
    const float v = (oc < 256) ? wq[oc*256 + ci] : wk[(oc-256)*256 + ci];
    Wf[frag_idx(oc, ci)] = f2bf(v);
    if (ci == 0) bias_all[oc] = (oc < 256) ? bq[oc] : bk[oc-256];
  } else {
    const int o = oc - 512;
    const float* wr = w128 + (size_t)o*256;
    float a = 0.f;
    for (int co = 0; co < 256; co++) a += wr[co] * wv[co*256 + ci];
    Wf[frag_idx(oc, ci)] = f2bf(a);
    if (ci == 0) {
      float s = 0.f;
      for (int co = 0; co < 256; co++) s += wr[co] * bv[co];
      bias_all[oc] = s;
    }
  }
}

// ---------------------------------------------------------------------------
// K2: MFMA feature GEMM (bf16 16x16x32 internally).  Grid (256,1): one block
//   per 64-px tile runs ALL 10 output tiles (ot).
//   ot 0..3 -> Qf8, 4..7 -> Kf8 (fp8 e4m3 chunks), ot 8..9 -> V fp32.
//   R10: Af B-fragments hoisted to 128 VGPR once per wave; x staged once.
// ---------------------------------------------------------------------------
__global__ __launch_bounds__(256) void k2_features(
    const float* __restrict__ x4, const float* __restrict__ x3,
    const ushort_t* __restrict__ Wf, const float* __restrict__ bias_all,
    uchar_t* __restrict__ Qf8, uchar_t* __restrict__ Kf8, float* __restrict__ V)
{
  __shared__ ushort_t Af[32*512];      // 32 KB
  __shared__ ushort_t Wl[2][32*512];   // 2 x 32 KB
  __shared__ ushort_t Lt[64*72];       // repack buffer (bf16)

  const int tid = threadIdx.x;
  const int w = tid >> 6, lane = tid & 63;
  const int mrow = lane & 15, quad = lane >> 4;
  const int ln31 = lane & 31, half = lane >> 5;

  const int px0 = blockIdx.x * 64;
  const int src = px0 >> 13, b = (px0 >> 10) & 7, hw0 = px0 & 1023;
  const float* xp = (src ? x3 : x4) + (size_t)b*262144;

  // prologue: W-frags for ot=0 -> Wl[0]
  for (int kb = 0; kb < 8; kb++)
    gl_lds16(Wf + ((size_t)(w*8 + kb)<<9) + lane*8,
             &Wl[0][(w*8+kb)*512]);

  {
    const int hw = hw0 + w*16 + mrow;
    for (int kb = 0; kb < 8; kb++) {
      const int ch0 = kb*32 + quad*8;
      bf16x8 pk;
      #pragma unroll
      for (int j = 0; j < 8; j++)
        ((ushort_t*)&pk)[j] = f2bf(xp[(size_t)(ch0 + j)*1024 + hw]);
      *(bf16x8*)&Af[(w*8 + kb)*512 + lane*8] = pk;
    }
  }
  __syncthreads();

  // hoist B-fragments (ot-invariant) into registers: 32 x bf16x8 = 128 VGPR
  bf16x8 bb[4][8];
  #pragma unroll
  for (int lg = 0; lg < 4; lg++)
    #pragma unroll
    for (int kb = 0; kb < 8; kb++)
      bb[lg][kb] = *(const bf16x8*)&Af[(lg*8 + kb)*512 + lane*8];

  for (int ot = 0; ot < 10; ot++) {
    const int cbuf = ot & 1, nbuf = cbuf ^ 1;
    if (ot + 1 < 10) {
      for (int kb = 0; kb < 8; kb++)
        gl_lds16(Wf + ((size_t)(((ot+1)*4 + w)*8 + kb)<<9) + lane*8,
                 &Wl[nbuf][(w*8+kb)*512]);
      asm volatile("s_waitcnt vmcnt(8)" ::: "memory");
    } else {
      asm volatile("s_waitcnt vmcnt(0)" ::: "memory");
    }

    f32x4 acc[4];
    #pragma unroll
    for (int lg = 0; lg < 4; lg++) acc[lg] = (f32x4){0.f,0.f,0.f,0.f};
    #pragma unroll
    for (int kb = 0; kb < 8; kb++) {
      const bf16x8 a = *(const bf16x8*)&Wl[cbuf][(w*8 + kb)*512 + lane*8];
      #pragma unroll
      for (int lg = 0; lg < 4; lg++)
        acc[lg] = __builtin_amdgcn_mfma_f32_16x16x32_bf16(a, bb[lg][kb], acc[lg], 0, 0, 0);
    }
    const int ocl = w*16 + quad*4;
    const float4 bias4 = *(const float4*)&bias_all[ot*64 + ocl];

    if (ot < 8) {
      __syncthreads();
      #pragma unroll
      for (int lg = 0; lg < 4; lg++) {
        const int px = lg*16 + mrow;
        ushort4 pk;
        pk.x = f2bf(acc[lg][0] + bias4.x);
        pk.y = f2bf(acc[lg][1] + bias4.y);
        pk.z = f2bf(acc[lg][2] + bias4.z);
        pk.w = f2bf(acc[lg][3] + bias4.w);
        *(ushort4*)&Lt[px*72 + ocl] = pk;
      }
      __syncthreads();
      // emit one fp8 chunk per wave: wave w -> g = w>>1, e = w&1
      const int g = w >> 1, e = w & 1;
      const int row = g*32 + ln31;
      const ushort_t* lp = &Lt[row*72 + e*32 + half*8];
      float fl[8], fh[8];
      #pragma unroll
      for (int j = 0; j < 8; j++) { fl[j] = bf2f(lp[j]); fh[j] = bf2f(lp[16+j]); }
      int w0 = __builtin_amdgcn_cvt_pk_fp8_f32(fl[0], fl[1], 0, 0);
      w0     = __builtin_amdgcn_cvt_pk_fp8_f32(fl[2], fl[3], w0, 1);
      int w1 = __builtin_amdgcn_cvt_pk_fp8_f32(fl[4], fl[5], 0, 0);
      w1     = __builtin_amdgcn_cvt_pk_fp8_f32(fl[6], fl[7], w1, 1);
      int w2 = __builtin_amdgcn_cvt_pk_fp8_f32(fh[0], fh[1], 0, 0);
      w2     = __builtin_amdgcn_cvt_pk_fp8_f32(fh[2], fh[3], w2, 1);
      int w3 = __builtin_amdgcn_cvt_pk_fp8_f32(fh[4], fh[5], 0, 0);
      w3     = __builtin_amdgcn_cvt_pk_fp8_f32(fh[6], fh[7], w3, 1);
      uchar_t* dst = (ot < 4) ? Qf8 : Kf8;
      const size_t chunk = (size_t)((px0>>5) + g)*8 + (ot&3)*2 + e;
      int4 pk4; pk4.x = w0; pk4.y = w1; pk4.z = w2; pk4.w = w3;
      *(int4*)(dst + (chunk<<10) + lane*16) = pk4;
    } else {
      const int ocv0 = (ot-8)*64 + ocl;
      float* vb = V + (((size_t)(src*8 + b)*128) << 10) + hw0;
      #pragma unroll
      for (int lg = 0; lg < 4; lg++) {
        vb[(size_t)(ocv0+0)*1024 + lg*16 + mrow] = acc[lg][0] + bias4.x;
        vb[(size_t)(ocv0+1)*1024 + lg*16 + mrow] = acc[lg][1] + bias4.y;
        vb[(size_t)(ocv0+2)*1024 + lg*16 + mrow] = acc[lg][2] + bias4.z;
        vb[(size_t)(ocv0+3)*1024 + lg*16 + mrow] = acc[lg][3] + bias4.w;
      }
    }
  }
}

// ---------------------------------------------------------------------------
// K3: MX-scaled fp8 MFMA 32x32x64 (unit scales = plain fp8 at 2x rate).
//   Block = 512 rows x one key-batch (1024 cols), 8 waves x 64 rows (2 rg32),
//   2 waves/SIMD, LDS double-buffered 2x32KB, __syncthreads stage loop,
//   stage loop ROLLED (R3), asm-pinned ds_read pipeline + counted lgkmcnt +
//   sched_barrier (R8), setprio around bursts (R9).
//   R11: LATENCY FIX -- 4 chains/wave via K-split.  Accounting: one
//   mfma_scale_32x32x64 = 68.7 cy/SIMD issue interval; measured util 46%
//   with 2 chains/wave x 2 waves = 4 chains/SIMD => dependent-issue slack
//   4x68.7 = 275 cy < MFMA latency L~600 cy => pipe starves on its own
//   result latency (explains R8's null: LDS was never the critical path).
//   Split each (rg,cgl) accumulator into even/odd-u partial sums
//   (a0e,a0o,a1e,a1o; combined by one fp32 add before the rmax fold):
//   8 chains/SIMD => slack 550 cy ~ L => predicted util 70-90%.
//   Cost: +32 acc regs (peak live ~234 <= 256), +32 VALU add/cgl.
//   Numerics: 4-term fp32 chain -> 2+2 split = ~1 ulp change in S.
//   Pm layout: [batch(16)][row(16384)].  Grid 512 x 512 threads.
// ---------------------------------------------------------------------------
#define RD8A(FR, CGL)                                                       \
  _Pragma("unroll")                                                         \
  for (int t = 0; t < 8; t++)                                               \
    asm volatile("ds_read_b128 %0, %1 offset:%c2"                           \
                 : "=v"(FR[t]) : "v"(kb), "i"((CGL)*8192 + t*1024));

#define WAITK(N)                                                            \
  asm volatile("s_waitcnt lgkmcnt(" #N ")" ::: "memory");                   \
  __builtin_amdgcn_sched_barrier(0);

#define QK_BURST(FR)                                                        \
  {                                                                         \
    f32x16 a0e = zv, a0o = zv, a1e = zv, a1o = zv;                          \
    __builtin_amdgcn_s_setprio(1);                                          \
    _Pragma("unroll")                                                       \
    for (int u = 0; u < 4; u++) {                                           \
      const v8i bu = (v8i){FR[2*u][0],   FR[2*u][1],   FR[2*u][2],   FR[2*u][3], \
                           FR[2*u+1][0], FR[2*u+1][1], FR[2*u+1][2], FR[2*u+1][3]}; \
      if (u & 1) {                                                          \
        a0o = __builtin_amdgcn_mfma_scale_f32_32x32x64_f8f6f4(              \
            qa[0][u], bu, a0o, 0, 0, 0, 0x7F7F7F7F, 0, 0x7F7F7F7F);         \
        a1o = __builtin_amdgcn_mfma_scale_f32_32x32x64_f8f6f4(              \
            qa[1][u], bu, a1o, 0, 0, 0, 0x7F7F7F7F, 0, 0x7F7F7F7F);         \
      } else {                                                              \
        a0e = __builtin_amdgcn_mfma_scale_f32_32x32x64_f8f6f4(              \
            qa[0][u], bu, a0e, 0, 0, 0, 0x7F7F7F7F, 0, 0x7F7F7F7F);         \
        a1e = __builtin_amdgcn_mfma_scale_f32_32x32x64_f8f6f4(              \
            qa[1][u], bu, a1e, 0, 0, 0, 0x7F7F7F7F, 0, 0x7F7F7F7F);         \
      }                                                                     \
    }                                                                       \
    __builtin_amdgcn_s_setprio(0);                                          \
    _Pragma("unroll")                                                       \
    for (int i = 0; i < 16; i++) {                                          \
      rmax[0][i] = fmaxf(rmax[0][i], a0e[i] + a0o[i]);                      \
      rmax[1][i] = fmaxf(rmax[1][i], a1e[i] + a1o[i]);                      \
    }                                                                       \
  }

__global__ __launch_bounds__(512, 2) void k3_smax(
    const uchar_t* __restrict__ Qf8, const uchar_t* __restrict__ Kf8,
    float* __restrict__ Pm)
{
  __shared__ __align__(16) uchar_t Kl[2][32768];   // 2 x 32 KB

  const int tid = threadIdx.x;
  const int bt = blockIdx.x >> 5;      // key-batch 0..15
  const int rt = blockIdx.x & 31;      // row-tile (512 rows)
  const int w = tid >> 6, lane = tid & 63;   // w: 0..7
  const int ln31 = lane & 31, half = lane >> 5;

  const int rgb = rt*16 + w*2;         // wave's first row-grp32 (owns 2)
  const int ph = (blockIdx.x & 1)*4;   // stage-phase rotation (8 stages)

  // prologue: stage s=0: 32 chunks (4 cgl x 8 kp); wave w -> c = w*4..w*4+3
  #pragma unroll
  for (int q = 0; q < 4; q++) {
    const int c = w*4 + q;             // cgl = c>>3, kp = c&7
    const int cg = bt*32 + ph*4 + (c>>3);
    gl_lds16(Kf8 + (((size_t)cg*8 + (c&7))<<10) + lane*16, &Kl[0][c*1024]);
  }

  // Q fragments: 2 rg x 4 u-windows, v8i each (64 VGPR), resident whole kernel
  v8i qa[2][4];
  #pragma unroll
  for (int rg = 0; rg < 2; rg++)
    #pragma unroll
    for (int u = 0; u < 4; u++) {
      const int4 p0 = *(const int4*)(Qf8 + (((size_t)(rgb + rg)*8 + 2*u+0)<<10) + lane*16);
      const int4 p1 = *(const int4*)(Qf8 + (((size_t)(rgb + rg)*8 + 2*u+1)<<10) + lane*16);
      qa[rg][u] = (v8i){p0.x, p0.y, p0.z, p0.w, p1.x, p1.y, p1.z, p1.w};
    }

  f32x16 zv;
  #pragma unroll
  for (int i = 0; i < 16; i++) zv[i] = 0.f;
  f32x16 rmax[2];
  #pragma unroll
  for (int rg = 0; rg < 2; rg++)
    #pragma unroll
    for (int i = 0; i < 16; i++) rmax[rg][i] = -3.4e38f;

  const unsigned kb0 = lds_addr(&Kl[0][0]) + lane*16;
  const unsigned kb1 = lds_addr(&Kl[1][0]) + lane*16;

  #pragma unroll 1                      // KEEP ROLLED (R3: unroll -> spill)
  for (int s = 0; s < 8; s++) {
    __syncthreads();                   // stage s data visible; vmcnt drained
    if (s < 7) {
      const int sn = (s + 1 + ph) & 7;
      #pragma unroll
      for (int q = 0; q < 4; q++) {
        const int c = w*4 + q;
        const int cg = bt*32 + sn*4 + (c>>3);
        gl_lds16(Kf8 + (((size_t)cg*8 + (c&7))<<10) + lane*16,
                 &Kl[(s+1)&1][c*1024]);
      }
    }
    const unsigned kb = (s & 1) ? kb1 : kb0;

    v4i fA[8], fB[8];
    RD8A(fA, 0)                        // 8 outstanding
    RD8A(fB, 1)                        // 16 outstanding
    WAITK(8)                           // fA ready, fB in flight
    QK_BURST(fA)                       // cgl 0
    RD8A(fA, 2)                        // 16 outstanding (fB + fA')
    WAITK(8)                           // fB ready, fA' in flight
    QK_BURST(fB)                       // cgl 1
    RD8A(fB, 3)                        // 16 outstanding (fA' + fB')
    WAITK(8)                           // fA' ready, fB' in flight
    QK_BURST(fA)                       // cgl 2
    WAITK(0)                           // fB' ready; clean counter for barrier
    QK_BURST(fB)                       // cgl 3
  }

  // epilogue: per-row max over 32 cols (5 xor-shuffles in each 32-lane half)
  // C/D: col = lane&31, row = (reg&3) + 8*(reg>>2) + 4*half (shape-determined)
  #pragma unroll
  for (int rg = 0; rg < 2; rg++) {
    #pragma unroll
    for (int e = 0; e < 16; e++) {
      float v = rmax[rg][e];
      v = fmaxf(v, __shfl_xor(v, 1));
      v = fmaxf(v, __shfl_xor(v, 2));
      v = fmaxf(v, __shfl_xor(v, 4));
      v = fmaxf(v, __shfl_xor(v, 8));
      v = fmaxf(v, __shfl_xor(v, 16));
      if (ln31 == 0) {
        const int row = rt*512 + w*64 + rg*32 + (e&3) + 8*(e>>2) + 4*half;
        Pm[(size_t)bt*16384 + row] = v;
      }
    }
  }
}

// ---------------------------------------------------------------------------
// K4: the 32 distinct gate softmaxes, computed ONCE each.
//   Grid 32 = (b 8) x (gidx 4); SW[gidx][b][hw] = softmax weight row.
// ---------------------------------------------------------------------------
__global__ __launch_bounds__(256) void k4_smweights(
    const float* __restrict__ Pm, float* __restrict__ SW)
{
  __shared__ float xw[2][4];
  const int tid = threadIdx.x;
  const int b = blockIdx.x >> 2, gidx = blockIdx.x & 3;
  const int qset = gidx >> 1, side = gidx & 1;

  // logits for hw = tid*4 .. tid*4+3 (coalesced float4 per batch)
  const float4* Pm4 = (const float4*)(Pm + (size_t)side*8*16384 + qset*8192 + b*1024);
  float4 l = {0.f, 0.f, 0.f, 0.f};
  #pragma unroll
  for (int t = 0; t < 8; t++) {
    const float4 p = Pm4[t*4096 + tid];
    l.x += p.x; l.y += p.y; l.z += p.z; l.w += p.w;
  }
  const float sc = 0.125f * 0.0625f;   // mean over 8 batches * 1/sqrt(256)
  l.x *= sc; l.y *= sc; l.z *= sc; l.w *= sc;

  const int w = tid >> 6, lane = tid & 63;
  float m = fmaxf(fmaxf(l.x, l.y), fmaxf(l.z, l.w));
  #pragma unroll
  for (int d = 1; d < 64; d <<= 1) m = fmaxf(m, __shfl_xor(m, d));
  if (lane == 0) xw[0][w] = m;
  __syncthreads();
  m = fmaxf(fmaxf(xw[0][0], xw[0][1]), fmaxf(xw[0][2], xw[0][3]));

  float4 e;
  e.x = expf(l.x - m); e.y = expf(l.y - m);
  e.z = expf(l.z - m); e.w = expf(l.w - m);
  float s = e.x + e.y + e.z + e.w;
  #pragma unroll
  for (int d = 1; d < 64; d <<= 1) s += __shfl_xor(s, d);
  if (lane == 0) xw[1][w] = s;
  __syncthreads();
  s = xw[1][0] + xw[1][1] + xw[1][2] + xw[1][3];
  const float inv = 1.f / s;

  float4 r;
  r.x = e.x*inv; r.y = e.y*inv; r.z = e.z*inv; r.w = e.w*inv;
  *(float4*)&SW[((size_t)(gidx*8 + b) << 10) + (tid << 2)] = r;
}

// ---------------------------------------------------------------------------
// K5: pure streaming gate apply: out[b][ch][hw] = SW[gidx][b][hw] * V + b128.
//   Block = one (b, ch) pair, 256 threads x 1 float4.  Fully coalesced.
//   ch: [x34|a_x4|x43|b_x3]
// ---------------------------------------------------------------------------
__global__ __launch_bounds__(256) void k5_out(
    const float* __restrict__ V, const float* __restrict__ SW,
    const float* __restrict__ b128, float* __restrict__ out)
{
  const int tid = threadIdx.x;
  const int ch = blockIdx.x & 511, b = blockIdx.x >> 9;
  const int blk = ch >> 7, o = ch & 127;
  const int gidx = (blk == 0) ? 2 : (blk == 1) ? 0 : (blk == 2) ? 1 : 3;
  const int src = (blk >= 2) ? 1 : 0;

  const int hw0 = tid << 2;
  const float4 sw = *(const float4*)&SW[((size_t)(gidx*8 + b) << 10) + hw0];
  const float4 v = *(const float4*)&V[((size_t)((src*8 + b)*128 + o) << 10) + hw0];
  const float bias = b128[o];
  float4 r;
  r.x = sw.x*v.x + bias; r.y = sw.y*v.y + bias;
  r.z = sw.z*v.z + bias; r.w = sw.w*v.w + bias;
  *(float4*)&out[((size_t)(b*512 + ch) << 10) + hw0] = r;
}

// ---------------------------------------------------------------------------
extern "C" void kernel_launch(void* const* d_in, const int* in_sizes, int n_in,
                              void* d_out, int out_size, void* d_ws, size_t ws_size,
                              hipStream_t stream)
{
  const float* x4   = (const float*)d_in[0];
  const float* x3   = (const float*)d_in[1];
  const float* wq   = (const float*)d_in[2];
  const float* bq   = (const float*)d_in[3];
  const float* wk   = (const float*)d_in[4];
  const float* bk   = (const float*)d_in[5];
  const float* wv   = (const float*)d_in[6];
  const float* bv   = (const float*)d_in[7];
  const float* w128 = (const float*)d_in[8];
  const float* b128 = (const float*)d_in[9];
  float* out = (float*)d_out;

  char* ws = (char*)d_ws;
  uchar_t*  Qf8 = (uchar_t*)ws;  ws += (size_t)512*8*1024;      // 4 MB
  uchar_t*  Kf8 = (uchar_t*)ws;  ws += (size_t)512*8*1024;      // 4 MB
  float*    V   = (float*)ws;    ws += (size_t)2*8*128*1024*4;  // 8 MB
  float*    Pm  = (float*)ws;    ws += (size_t)16*16384*4;      // 1 MB
  ushort_t* Wf  = (ushort_t*)ws; ws += (size_t)640*256*2;       // 320 KB
  float* bias_all = (float*)ws;  ws += (size_t)640*4;           // 2.5 KB
  float* SW = (float*)ws;                                       // 128 KB

  k1_weights  <<<640,  256, 0, stream>>>(wq, bq, wk, bk, wv, bv, w128, Wf, bias_all);
  k2_features <<<256,  256, 0, stream>>>(x4, x3, Wf, bias_all, Qf8, Kf8, V);
  k3_smax     <<<512,  512, 0, stream>>>(Qf8, Kf8, Pm);
  k4_smweights<<<32,   256, 0, stream>>>(Pm, SW);
  k5_out      <<<4096, 256, 0, stream>>>(V, SW, b128, out);
}

// Round 12
// 181.122 us; speedup vs baseline: 1.2174x; 1.2174x over previous
//
#include <hip/hip_runtime.h>

typedef unsigned short ushort_t;
typedef unsigned char uchar_t;
typedef __attribute__((ext_vector_type(8))) short bf16x8;
typedef __attribute__((ext_vector_type(4))) float f32x4;
typedef __attribute__((ext_vector_type(16))) float f32x16;
typedef __attribute__((ext_vector_type(8))) int v8i;
typedef __attribute__((ext_vector_type(4))) int v4i;

__device__ __forceinline__ unsigned short f2bf(float f) {
  union { float f; unsigned int u; } v; v.f = f;
  unsigned int r = v.u + 0x7FFFu + ((v.u >> 16) & 1u);
  return (unsigned short)(r >> 16);
}

__device__ __forceinline__ float bf2f(unsigned short u) {
  union { unsigned int i; float f; } v; v.i = ((unsigned int)u) << 16;
  return v.f;
}

__device__ __forceinline__ void gl_lds16(const void* gsrc, void* ldst) {
  __builtin_amdgcn_global_load_lds(
      (const __attribute__((address_space(1))) void*)gsrc,
      (__attribute__((address_space(3))) void*)ldst, 16, 0, 0);
}

__device__ __forceinline__ unsigned lds_addr(void* p) {
  return (unsigned)(uintptr_t)(__attribute__((address_space(3))) void*)p;
}

__device__ __forceinline__ int frag_idx(int oc, int ci) {
  return (((oc>>4)*8 + (ci>>5))<<9) + ((((ci>>3)&3)*16 + (oc&15))<<3) + (ci&7);
}

// ---------------------------------------------------------------------------
// K1: fragment-major bf16 weight bank Wf[640][256] (Q=wq, K=wk, V=w128@wv)
//     + bias_all[640].  Blocks 0..511: copy/cast QK.  512..639: V-fold, 1 oc
//     per block.
// ---------------------------------------------------------------------------
__global__ __launch_bounds__(256) void k1_weights(
    const float* __restrict__ wq, const float* __restrict__ bq,
    const float* __restrict__ wk, const float* __restrict__ bk,
    const float* __restrict__ wv, const float* __restrict__ bv,
    const float* __restrict__ w128,
    ushort_t* __restrict__ Wf, float* __restrict__ bias_all)
{
  const int ci = threadIdx.x;
  const int oc = blockIdx.x;
  if (oc < 512) {
    const float v = (oc < 256) ? wq[oc*256 + ci] : wk[(oc-256)*256 + ci];
    Wf[frag_idx(oc, ci)] = f2bf(v);
    if (ci == 0) bias_all[oc] = (oc < 256) ? bq[oc] : bk[oc-256];
  } else {
    const int o = oc - 512;
    const float* wr = w128 + (size_t)o*256;
    float a = 0.f;
    for (int co = 0; co < 256; co++) a += wr[co] * wv[co*256 + ci];
    Wf[frag_idx(oc, ci)] = f2bf(a);
    if (ci == 0) {
      float s = 0.f;
      for (int co = 0; co < 256; co++) s += wr[co] * bv[co];
      bias_all[oc] = s;
    }
  }
}

// ---------------------------------------------------------------------------
// K2: MFMA feature GEMM (bf16 16x16x32 internally).  Grid (256,1): one block
//   per 64-px tile runs ALL 10 output tiles (ot).
//   ot 0..3 -> Qf8, 4..7 -> Kf8 (fp8 e4m3 chunks), ot 8..9 -> V fp32.
//   R10: Af B-fragments hoisted to 128 VGPR once per wave; x staged once.
// ---------------------------------------------------------------------------
__global__ __launch_bounds__(256) void k2_features(
    const float* __restrict__ x4, const float* __restrict__ x3,
    const ushort_t* __restrict__ Wf, const float* __restrict__ bias_all,
    uchar_t* __restrict__ Qf8, uchar_t* __restrict__ Kf8, float* __restrict__ V)
{
  __shared__ ushort_t Af[32*512];      // 32 KB
  __shared__ ushort_t Wl[2][32*512];   // 2 x 32 KB
  __shared__ ushort_t Lt[64*72];       // repack buffer (bf16)

  const int tid = threadIdx.x;
  const int w = tid >> 6, lane = tid & 63;
  const int mrow = lane & 15, quad = lane >> 4;
  const int ln31 = lane & 31, half = lane >> 5;

  const int px0 = blockIdx.x * 64;
  const int src = px0 >> 13, b = (px0 >> 10) & 7, hw0 = px0 & 1023;
  const float* xp = (src ? x3 : x4) + (size_t)b*262144;

  // prologue: W-frags for ot=0 -> Wl[0]
  for (int kb = 0; kb < 8; kb++)
    gl_lds16(Wf + ((size_t)(w*8 + kb)<<9) + lane*8,
             &Wl[0][(w*8+kb)*512]);

  {
    const int hw = hw0 + w*16 + mrow;
    for (int kb = 0; kb < 8; kb++) {
      const int ch0 = kb*32 + quad*8;
      bf16x8 pk;
      #pragma unroll
      for (int j = 0; j < 8; j++)
        ((ushort_t*)&pk)[j] = f2bf(xp[(size_t)(ch0 + j)*1024 + hw]);
      *(bf16x8*)&Af[(w*8 + kb)*512 + lane*8] = pk;
    }
  }
  __syncthreads();

  // hoist B-fragments (ot-invariant) into registers: 32 x bf16x8 = 128 VGPR
  bf16x8 bb[4][8];
  #pragma unroll
  for (int lg = 0; lg < 4; lg++)
    #pragma unroll
    for (int kb = 0; kb < 8; kb++)
      bb[lg][kb] = *(const bf16x8*)&Af[(lg*8 + kb)*512 + lane*8];

  for (int ot = 0; ot < 10; ot++) {
    const int cbuf = ot & 1, nbuf = cbuf ^ 1;
    if (ot + 1 < 10) {
      for (int kb = 0; kb < 8; kb++)
        gl_lds16(Wf + ((size_t)(((ot+1)*4 + w)*8 + kb)<<9) + lane*8,
                 &Wl[nbuf][(w*8+kb)*512]);
      asm volatile("s_waitcnt vmcnt(8)" ::: "memory");
    } else {
      asm volatile("s_waitcnt vmcnt(0)" ::: "memory");
    }

    f32x4 acc[4];
    #pragma unroll
    for (int lg = 0; lg < 4; lg++) acc[lg] = (f32x4){0.f,0.f,0.f,0.f};
    #pragma unroll
    for (int kb = 0; kb < 8; kb++) {
      const bf16x8 a = *(const bf16x8*)&Wl[cbuf][(w*8 + kb)*512 + lane*8];
      #pragma unroll
      for (int lg = 0; lg < 4; lg++)
        acc[lg] = __builtin_amdgcn_mfma_f32_16x16x32_bf16(a, bb[lg][kb], acc[lg], 0, 0, 0);
    }
    const int ocl = w*16 + quad*4;
    const float4 bias4 = *(const float4*)&bias_all[ot*64 + ocl];

    if (ot < 8) {
      __syncthreads();
      #pragma unroll
      for (int lg = 0; lg < 4; lg++) {
        const int px = lg*16 + mrow;
        ushort4 pk;
        pk.x = f2bf(acc[lg][0] + bias4.x);
        pk.y = f2bf(acc[lg][1] + bias4.y);
        pk.z = f2bf(acc[lg][2] + bias4.z);
        pk.w = f2bf(acc[lg][3] + bias4.w);
        *(ushort4*)&Lt[px*72 + ocl] = pk;
      }
      __syncthreads();
      // emit one fp8 chunk per wave: wave w -> g = w>>1, e = w&1
      const int g = w >> 1, e = w & 1;
      const int row = g*32 + ln31;
      const ushort_t* lp = &Lt[row*72 + e*32 + half*8];
      float fl[8], fh[8];
      #pragma unroll
      for (int j = 0; j < 8; j++) { fl[j] = bf2f(lp[j]); fh[j] = bf2f(lp[16+j]); }
      int w0 = __builtin_amdgcn_cvt_pk_fp8_f32(fl[0], fl[1], 0, 0);
      w0     = __builtin_amdgcn_cvt_pk_fp8_f32(fl[2], fl[3], w0, 1);
      int w1 = __builtin_amdgcn_cvt_pk_fp8_f32(fl[4], fl[5], 0, 0);
      w1     = __builtin_amdgcn_cvt_pk_fp8_f32(fl[6], fl[7], w1, 1);
      int w2 = __builtin_amdgcn_cvt_pk_fp8_f32(fh[0], fh[1], 0, 0);
      w2     = __builtin_amdgcn_cvt_pk_fp8_f32(fh[2], fh[3], w2, 1);
      int w3 = __builtin_amdgcn_cvt_pk_fp8_f32(fh[4], fh[5], 0, 0);
      w3     = __builtin_amdgcn_cvt_pk_fp8_f32(fh[6], fh[7], w3, 1);
      uchar_t* dst = (ot < 4) ? Qf8 : Kf8;
      const size_t chunk = (size_t)((px0>>5) + g)*8 + (ot&3)*2 + e;
      int4 pk4; pk4.x = w0; pk4.y = w1; pk4.z = w2; pk4.w = w3;
      *(int4*)(dst + (chunk<<10) + lane*16) = pk4;
    } else {
      const int ocv0 = (ot-8)*64 + ocl;
      float* vb = V + (((size_t)(src*8 + b)*128) << 10) + hw0;
      #pragma unroll
      for (int lg = 0; lg < 4; lg++) {
        vb[(size_t)(ocv0+0)*1024 + lg*16 + mrow] = acc[lg][0] + bias4.x;
        vb[(size_t)(ocv0+1)*1024 + lg*16 + mrow] = acc[lg][1] + bias4.y;
        vb[(size_t)(ocv0+2)*1024 + lg*16 + mrow] = acc[lg][2] + bias4.z;
        vb[(size_t)(ocv0+3)*1024 + lg*16 + mrow] = acc[lg][3] + bias4.w;
      }
    }
  }
}

// ---------------------------------------------------------------------------
// K3: MX-scaled fp8 MFMA 32x32x64 (unit scales = plain fp8 at 2x rate).
//   Block = 512 rows x one key-batch (1024 cols), 8 waves x 64 rows (2 rg32),
//   2 waves/SIMD, LDS double-buffered 2x32KB, __syncthreads stage loop,
//   stage loop ROLLED (R3), setprio around bursts (R9).
//   R12: 4 chains/wave, NO fragment read-ahead.  R11 proved 4 chains + fB
//   pipeline = spill (qa64+frags64+acc64+rmax32 > 256; 89 MB scratch).
//   R8 valued the read-ahead at only ~1.1us, so trade it for the chains:
//   per cgl = RD8A -> lgkmcnt(0) -> 8-MFMA burst over 4 independent chains
//   (a0e,a0o,a1e,a1o; even/odd-u K-split, one fp32 add before fold).
//   Liveness: qa64 + fA32 + acc64 + rmax32 + addr ~ 215 <= 256, no spill.
//   Chains/SIMD 4 -> 8 (m119 saturates ~16): tests the MFMA-latency theory
//   cleanly vs R10 (2 chains + pipeline, 63.3us @ 46% MfmaUtil).
//   Pm layout: [batch(16)][row(16384)].  Grid 512 x 512 threads.
// ---------------------------------------------------------------------------
#define RD8A(FR, CGL)                                                       \
  _Pragma("unroll")                                                         \
  for (int t = 0; t < 8; t++)                                               \
    asm volatile("ds_read_b128 %0, %1 offset:%c2"                           \
                 : "=v"(FR[t]) : "v"(kb), "i"((CGL)*8192 + t*1024));

#define WAITK0                                                              \
  asm volatile("s_waitcnt lgkmcnt(0)" ::: "memory");                        \
  __builtin_amdgcn_sched_barrier(0);

#define QK_BURST(FR)                                                        \
  {                                                                         \
    f32x16 a0e = zv, a0o = zv, a1e = zv, a1o = zv;                          \
    __builtin_amdgcn_s_setprio(1);                                          \
    _Pragma("unroll")                                                       \
    for (int u = 0; u < 4; u++) {                                           \
      const v8i bu = (v8i){FR[2*u][0],   FR[2*u][1],   FR[2*u][2],   FR[2*u][3], \
                           FR[2*u+1][0], FR[2*u+1][1], FR[2*u+1][2], FR[2*u+1][3]}; \
      if (u & 1) {                                                          \
        a0o = __builtin_amdgcn_mfma_scale_f32_32x32x64_f8f6f4(              \
            qa[0][u], bu, a0o, 0, 0, 0, 0x7F7F7F7F, 0, 0x7F7F7F7F);         \
        a1o = __builtin_amdgcn_mfma_scale_f32_32x32x64_f8f6f4(              \
            qa[1][u], bu, a1o, 0, 0, 0, 0x7F7F7F7F, 0, 0x7F7F7F7F);         \
      } else {                                                              \
        a0e = __builtin_amdgcn_mfma_scale_f32_32x32x64_f8f6f4(              \
            qa[0][u], bu, a0e, 0, 0, 0, 0x7F7F7F7F, 0, 0x7F7F7F7F);         \
        a1e = __builtin_amdgcn_mfma_scale_f32_32x32x64_f8f6f4(              \
            qa[1][u], bu, a1e, 0, 0, 0, 0x7F7F7F7F, 0, 0x7F7F7F7F);         \
      }                                                                     \
    }                                                                       \
    __builtin_amdgcn_s_setprio(0);                                          \
    _Pragma("unroll")                                                       \
    for (int i = 0; i < 16; i++) {                                          \
      rmax[0][i] = fmaxf(rmax[0][i], a0e[i] + a0o[i]);                      \
      rmax[1][i] = fmaxf(rmax[1][i], a1e[i] + a1o[i]);                      \
    }                                                                       \
  }

__global__ __launch_bounds__(512, 2) void k3_smax(
    const uchar_t* __restrict__ Qf8, const uchar_t* __restrict__ Kf8,
    float* __restrict__ Pm)
{
  __shared__ __align__(16) uchar_t Kl[2][32768];   // 2 x 32 KB

  const int tid = threadIdx.x;
  const int bt = blockIdx.x >> 5;      // key-batch 0..15
  const int rt = blockIdx.x & 31;      // row-tile (512 rows)
  const int w = tid >> 6, lane = tid & 63;   // w: 0..7
  const int ln31 = lane & 31, half = lane >> 5;

  const int rgb = rt*16 + w*2;         // wave's first row-grp32 (owns 2)
  const int ph = (blockIdx.x & 1)*4;   // stage-phase rotation (8 stages)

  // prologue: stage s=0: 32 chunks (4 cgl x 8 kp); wave w -> c = w*4..w*4+3
  #pragma unroll
  for (int q = 0; q < 4; q++) {
    const int c = w*4 + q;             // cgl = c>>3, kp = c&7
    const int cg = bt*32 + ph*4 + (c>>3);
    gl_lds16(Kf8 + (((size_t)cg*8 + (c&7))<<10) + lane*16, &Kl[0][c*1024]);
  }

  // Q fragments: 2 rg x 4 u-windows, v8i each (64 VGPR), resident whole kernel
  v8i qa[2][4];
  #pragma unroll
  for (int rg = 0; rg < 2; rg++)
    #pragma unroll
    for (int u = 0; u < 4; u++) {
      const int4 p0 = *(const int4*)(Qf8 + (((size_t)(rgb + rg)*8 + 2*u+0)<<10) + lane*16);
      const int4 p1 = *(const int4*)(Qf8 + (((size_t)(rgb + rg)*8 + 2*u+1)<<10) + lane*16);
      qa[rg][u] = (v8i){p0.x, p0.y, p0.z, p0.w, p1.x, p1.y, p1.z, p1.w};
    }

  f32x16 zv;
  #pragma unroll
  for (int i = 0; i < 16; i++) zv[i] = 0.f;
  f32x16 rmax[2];
  #pragma unroll
  for (int rg = 0; rg < 2; rg++)
    #pragma unroll
    for (int i = 0; i < 16; i++) rmax[rg][i] = -3.4e38f;

  const unsigned kb0 = lds_addr(&Kl[0][0]) + lane*16;
  const unsigned kb1 = lds_addr(&Kl[1][0]) + lane*16;

  #pragma unroll 1                      // KEEP ROLLED (R3: unroll -> spill)
  for (int s = 0; s < 8; s++) {
    __syncthreads();                   // stage s data visible; vmcnt drained
    if (s < 7) {
      const int sn = (s + 1 + ph) & 7;
      #pragma unroll
      for (int q = 0; q < 4; q++) {
        const int c = w*4 + q;
        const int cg = bt*32 + sn*4 + (c>>3);
        gl_lds16(Kf8 + (((size_t)cg*8 + (c&7))<<10) + lane*16,
                 &Kl[(s+1)&1][c*1024]);
      }
    }
    const unsigned kb = (s & 1) ? kb1 : kb0;

    v4i fA[8];
    RD8A(fA, 0)
    WAITK0
    QK_BURST(fA)                       // cgl 0
    RD8A(fA, 1)
    WAITK0
    QK_BURST(fA)                       // cgl 1
    RD8A(fA, 2)
    WAITK0
    QK_BURST(fA)                       // cgl 2
    RD8A(fA, 3)
    WAITK0
    QK_BURST(fA)                       // cgl 3
  }

  // epilogue: per-row max over 32 cols (5 xor-shuffles in each 32-lane half)
  // C/D: col = lane&31, row = (reg&3) + 8*(reg>>2) + 4*half (shape-determined)
  #pragma unroll
  for (int rg = 0; rg < 2; rg++) {
    #pragma unroll
    for (int e = 0; e < 16; e++) {
      float v = rmax[rg][e];
      v = fmaxf(v, __shfl_xor(v, 1));
      v = fmaxf(v, __shfl_xor(v, 2));
      v = fmaxf(v, __shfl_xor(v, 4));
      v = fmaxf(v, __shfl_xor(v, 8));
      v = fmaxf(v, __shfl_xor(v, 16));
      if (ln31 == 0) {
        const int row = rt*512 + w*64 + rg*32 + (e&3) + 8*(e>>2) + 4*half;
        Pm[(size_t)bt*16384 + row] = v;
      }
    }
  }
}

// ---------------------------------------------------------------------------
// K4: the 32 distinct gate softmaxes, computed ONCE each.
//   Grid 32 = (b 8) x (gidx 4); SW[gidx][b][hw] = softmax weight row.
// ---------------------------------------------------------------------------
__global__ __launch_bounds__(256) void k4_smweights(
    const float* __restrict__ Pm, float* __restrict__ SW)
{
  __shared__ float xw[2][4];
  const int tid = threadIdx.x;
  const int b = blockIdx.x >> 2, gidx = blockIdx.x & 3;
  const int qset = gidx >> 1, side = gidx & 1;

  // logits for hw = tid*4 .. tid*4+3 (coalesced float4 per batch)
  const float4* Pm4 = (const float4*)(Pm + (size_t)side*8*16384 + qset*8192 + b*1024);
  float4 l = {0.f, 0.f, 0.f, 0.f};
  #pragma unroll
  for (int t = 0; t < 8; t++) {
    const float4 p = Pm4[t*4096 + tid];
    l.x += p.x; l.y += p.y; l.z += p.z; l.w += p.w;
  }
  const float sc = 0.125f * 0.0625f;   // mean over 8 batches * 1/sqrt(256)
  l.x *= sc; l.y *= sc; l.z *= sc; l.w *= sc;

  const int w = tid >> 6, lane = tid & 63;
  float m = fmaxf(fmaxf(l.x, l.y), fmaxf(l.z, l.w));
  #pragma unroll
  for (int d = 1; d < 64; d <<= 1) m = fmaxf(m, __shfl_xor(m, d));
  if (lane == 0) xw[0][w] = m;
  __syncthreads();
  m = fmaxf(fmaxf(xw[0][0], xw[0][1]), fmaxf(xw[0][2], xw[0][3]));

  float4 e;
  e.x = expf(l.x - m); e.y = expf(l.y - m);
  e.z = expf(l.z - m); e.w = expf(l.w - m);
  float s = e.x + e.y + e.z + e.w;
  #pragma unroll
  for (int d = 1; d < 64; d <<= 1) s += __shfl_xor(s, d);
  if (lane == 0) xw[1][w] = s;
  __syncthreads();
  s = xw[1][0] + xw[1][1] + xw[1][2] + xw[1][3];
  const float inv = 1.f / s;

  float4 r;
  r.x = e.x*inv; r.y = e.y*inv; r.z = e.z*inv; r.w = e.w*inv;
  *(float4*)&SW[((size_t)(gidx*8 + b) << 10) + (tid << 2)] = r;
}

// ---------------------------------------------------------------------------
// K5: pure streaming gate apply: out[b][ch][hw] = SW[gidx][b][hw] * V + b128.
//   Block = one (b, ch) pair, 256 threads x 1 float4.  Fully coalesced.
//   ch: [x34|a_x4|x43|b_x3]
// ---------------------------------------------------------------------------
__global__ __launch_bounds__(256) void k5_out(
    const float* __restrict__ V, const float* __restrict__ SW,
    const float* __restrict__ b128, float* __restrict__ out)
{
  const int tid = threadIdx.x;
  const int ch = blockIdx.x & 511, b = blockIdx.x >> 9;
  const int blk = ch >> 7, o = ch & 127;
  const int gidx = (blk == 0) ? 2 : (blk == 1) ? 0 : (blk == 2) ? 1 : 3;
  const int src = (blk >= 2) ? 1 : 0;

  const int hw0 = tid << 2;
  const float4 sw = *(const float4*)&SW[((size_t)(gidx*8 + b) << 10) + hw0];
  const float4 v = *(const float4*)&V[((size_t)((src*8 + b)*128 + o) << 10) + hw0];
  const float bias = b128[o];
  float4 r;
  r.x = sw.x*v.x + bias; r.y = sw.y*v.y + bias;
  r.z = sw.z*v.z + bias; r.w = sw.w*v.w + bias;
  *(float4*)&out[((size_t)(b*512 + ch) << 10) + hw0] = r;
}

// ---------------------------------------------------------------------------
extern "C" void kernel_launch(void* const* d_in, const int* in_sizes, int n_in,
                              void* d_out, int out_size, void* d_ws, size_t ws_size,
                              hipStream_t stream)
{
  const float* x4   = (const float*)d_in[0];
  const float* x3   = (const float*)d_in[1];
  const float* wq   = (const float*)d_in[2];
  const float* bq   = (const float*)d_in[3];
  const float* wk   = (const float*)d_in[4];
  const float* bk   = (const float*)d_in[5];
  const float* wv   = (const float*)d_in[6];
  const float* bv   = (const float*)d_in[7];
  const float* w128 = (const float*)d_in[8];
  const float* b128 = (const float*)d_in[9];
  float* out = (float*)d_out;

  char* ws = (char*)d_ws;
  uchar_t*  Qf8 = (uchar_t*)ws;  ws += (size_t)512*8*1024;      // 4 MB
  uchar_t*  Kf8 = (uchar_t*)ws;  ws += (size_t)512*8*1024;      // 4 MB
  float*    V   = (float*)ws;    ws += (size_t)2*8*128*1024*4;  // 8 MB
  float*    Pm  = (float*)ws;    ws += (size_t)16*16384*4;      // 1 MB
  ushort_t* Wf  = (ushort_t*)ws; ws += (size_t)640*256*2;       // 320 KB
  float* bias_all = (float*)ws;  ws += (size_t)640*4;           // 2.5 KB
  float* SW = (float*)ws;                                       // 128 KB

  k1_weights  <<<640,  256, 0, stream>>>(wq, bq, wk, bk, wv, bv, w128, Wf, bias_all);
  k2_features <<<256,  256, 0, stream>>>(x4, x3, Wf, bias_all, Qf8, Kf8, V);
  k3_smax     <<<512,  512, 0, stream>>>(Qf8, Kf8, Pm);
  k4_smweights<<<32,   256, 0, stream>>>(Pm, SW);
  k5_out      <<<4096, 256, 0, stream>>>(V, SW, b128, out);
}

// Round 13
// 177.332 us; speedup vs baseline: 1.2434x; 1.0214x over previous
//
#include <hip/hip_runtime.h>

typedef unsigned short ushort_t;
typedef unsigned char uchar_t;
typedef __attribute__((ext_vector_type(8))) short bf16x8;
typedef __attribute__((ext_vector_type(4))) float f32x4;
typedef __attribute__((ext_vector_type(16))) float f32x16;
typedef __attribute__((ext_vector_type(8))) int v8i;
typedef __attribute__((ext_vector_type(4))) int v4i;

__device__ __forceinline__ unsigned short f2bf(float f) {
  union { float f; unsigned int u; } v; v.f = f;
  unsigned int r = v.u + 0x7FFFu + ((v.u >> 16) & 1u);
  return (unsigned short)(r >> 16);
}

__device__ __forceinline__ float bf2f(unsigned short u) {
  union { unsigned int i; float f; } v; v.i = ((unsigned int)u) << 16;
  return v.f;
}

__device__ __forceinline__ void gl_lds16(const void* gsrc, void* ldst) {
  __builtin_amdgcn_global_load_lds(
      (const __attribute__((address_space(1))) void*)gsrc,
      (__attribute__((address_space(3))) void*)ldst, 16, 0, 0);
}

__device__ __forceinline__ unsigned lds_addr(void* p) {
  return (unsigned)(uintptr_t)(__attribute__((address_space(3))) void*)p;
}

__device__ __forceinline__ int frag_idx(int oc, int ci) {
  return (((oc>>4)*8 + (ci>>5))<<9) + ((((ci>>3)&3)*16 + (oc&15))<<3) + (ci&7);
}

// ---------------------------------------------------------------------------
// K1: fragment-major bf16 weight bank Wf[640][256] (Q=wq, K=wk, V=w128@wv)
//     + bias_all[640].  Blocks 0..511: copy/cast QK.  512..639: V-fold, 1 oc
//     per block.
// ---------------------------------------------------------------------------
__global__ __launch_bounds__(256) void k1_weights(
    const float* __restrict__ wq, const float* __restrict__ bq,
    const float* __restrict__ wk, const float* __restrict__ bk,
    const float* __restrict__ wv, const float* __restrict__ bv,
    const float* __restrict__ w128,
    ushort_t* __restrict__ Wf, float* __restrict__ bias_all)
{
  const int ci = threadIdx.x;
  const int oc = blockIdx.x;
  if (oc < 512) {
    const float v = (oc < 256) ? wq[oc*256 + ci] : wk[(oc-256)*256 + ci];
    Wf[frag_idx(oc, ci)] = f2bf(v);
    if (ci == 0) bias_all[oc] = (oc < 256) ? bq[oc] : bk[oc-256];
  } else {
    const int o = oc - 512;
    const float* wr = w128 + (size_t)o*256;
    float a = 0.f;
    for (int co = 0; co < 256; co++) a += wr[co] * wv[co*256 + ci];
    Wf[frag_idx(oc, ci)] = f2bf(a);
    if (ci == 0) {
      float s = 0.f;
      for (int co = 0; co < 256; co++) s += wr[co] * bv[co];
      bias_all[oc] = s;
    }
  }
}

// ---------------------------------------------------------------------------
// K2: MFMA feature GEMM (bf16 16x16x32 internally).  Grid (256,1): one block
//   per 64-px tile runs ALL 10 output tiles (ot).
//   ot 0..3 -> Qf8, 4..7 -> Kf8 (fp8 e4m3 chunks), ot 8..9 -> V fp32.
//   R10: Af B-fragments hoisted to 128 VGPR once per wave; x staged once.
// ---------------------------------------------------------------------------
__global__ __launch_bounds__(256) void k2_features(
    const float* __restrict__ x4, const float* __restrict__ x3,
    const ushort_t* __restrict__ Wf, const float* __restrict__ bias_all,
    uchar_t* __restrict__ Qf8, uchar_t* __restrict__ Kf8, float* __restrict__ V)
{
  __shared__ ushort_t Af[32*512];      // 32 KB
  __shared__ ushort_t Wl[2][32*512];   // 2 x 32 KB
  __shared__ ushort_t Lt[64*72];       // repack buffer (bf16)

  const int tid = threadIdx.x;
  const int w = tid >> 6, lane = tid & 63;
  const int mrow = lane & 15, quad = lane >> 4;
  const int ln31 = lane & 31, half = lane >> 5;

  const int px0 = blockIdx.x * 64;
  const int src = px0 >> 13, b = (px0 >> 10) & 7, hw0 = px0 & 1023;
  const float* xp = (src ? x3 : x4) + (size_t)b*262144;

  // prologue: W-frags for ot=0 -> Wl[0]
  for (int kb = 0; kb < 8; kb++)
    gl_lds16(Wf + ((size_t)(w*8 + kb)<<9) + lane*8,
             &Wl[0][(w*8+kb)*512]);

  {
    const int hw = hw0 + w*16 + mrow;
    for (int kb = 0; kb < 8; kb++) {
      const int ch0 = kb*32 + quad*8;
      bf16x8 pk;
      #pragma unroll
      for (int j = 0; j < 8; j++)
        ((ushort_t*)&pk)[j] = f2bf(xp[(size_t)(ch0 + j)*1024 + hw]);
      *(bf16x8*)&Af[(w*8 + kb)*512 + lane*8] = pk;
    }
  }
  __syncthreads();

  // hoist B-fragments (ot-invariant) into registers: 32 x bf16x8 = 128 VGPR
  bf16x8 bb[4][8];
  #pragma unroll
  for (int lg = 0; lg < 4; lg++)
    #pragma unroll
    for (int kb = 0; kb < 8; kb++)
      bb[lg][kb] = *(const bf16x8*)&Af[(lg*8 + kb)*512 + lane*8];

  for (int ot = 0; ot < 10; ot++) {
    const int cbuf = ot & 1, nbuf = cbuf ^ 1;
    if (ot + 1 < 10) {
      for (int kb = 0; kb < 8; kb++)
        gl_lds16(Wf + ((size_t)(((ot+1)*4 + w)*8 + kb)<<9) + lane*8,
                 &Wl[nbuf][(w*8+kb)*512]);
      asm volatile("s_waitcnt vmcnt(8)" ::: "memory");
    } else {
      asm volatile("s_waitcnt vmcnt(0)" ::: "memory");
    }

    f32x4 acc[4];
    #pragma unroll
    for (int lg = 0; lg < 4; lg++) acc[lg] = (f32x4){0.f,0.f,0.f,0.f};
    #pragma unroll
    for (int kb = 0; kb < 8; kb++) {
      const bf16x8 a = *(const bf16x8*)&Wl[cbuf][(w*8 + kb)*512 + lane*8];
      #pragma unroll
      for (int lg = 0; lg < 4; lg++)
        acc[lg] = __builtin_amdgcn_mfma_f32_16x16x32_bf16(a, bb[lg][kb], acc[lg], 0, 0, 0);
    }
    const int ocl = w*16 + quad*4;
    const float4 bias4 = *(const float4*)&bias_all[ot*64 + ocl];

    if (ot < 8) {
      __syncthreads();
      #pragma unroll
      for (int lg = 0; lg < 4; lg++) {
        const int px = lg*16 + mrow;
        ushort4 pk;
        pk.x = f2bf(acc[lg][0] + bias4.x);
        pk.y = f2bf(acc[lg][1] + bias4.y);
        pk.z = f2bf(acc[lg][2] + bias4.z);
        pk.w = f2bf(acc[lg][3] + bias4.w);
        *(ushort4*)&Lt[px*72 + ocl] = pk;
      }
      __syncthreads();
      // emit one fp8 chunk per wave: wave w -> g = w>>1, e = w&1
      const int g = w >> 1, e = w & 1;
      const int row = g*32 + ln31;
      const ushort_t* lp = &Lt[row*72 + e*32 + half*8];
      float fl[8], fh[8];
      #pragma unroll
      for (int j = 0; j < 8; j++) { fl[j] = bf2f(lp[j]); fh[j] = bf2f(lp[16+j]); }
      int w0 = __builtin_amdgcn_cvt_pk_fp8_f32(fl[0], fl[1], 0, 0);
      w0     = __builtin_amdgcn_cvt_pk_fp8_f32(fl[2], fl[3], w0, 1);
      int w1 = __builtin_amdgcn_cvt_pk_fp8_f32(fl[4], fl[5], 0, 0);
      w1     = __builtin_amdgcn_cvt_pk_fp8_f32(fl[6], fl[7], w1, 1);
      int w2 = __builtin_amdgcn_cvt_pk_fp8_f32(fh[0], fh[1], 0, 0);
      w2     = __builtin_amdgcn_cvt_pk_fp8_f32(fh[2], fh[3], w2, 1);
      int w3 = __builtin_amdgcn_cvt_pk_fp8_f32(fh[4], fh[5], 0, 0);
      w3     = __builtin_amdgcn_cvt_pk_fp8_f32(fh[6], fh[7], w3, 1);
      uchar_t* dst = (ot < 4) ? Qf8 : Kf8;
      const size_t chunk = (size_t)((px0>>5) + g)*8 + (ot&3)*2 + e;
      int4 pk4; pk4.x = w0; pk4.y = w1; pk4.z = w2; pk4.w = w3;
      *(int4*)(dst + (chunk<<10) + lane*16) = pk4;
    } else {
      const int ocv0 = (ot-8)*64 + ocl;
      float* vb = V + (((size_t)(src*8 + b)*128) << 10) + hw0;
      #pragma unroll
      for (int lg = 0; lg < 4; lg++) {
        vb[(size_t)(ocv0+0)*1024 + lg*16 + mrow] = acc[lg][0] + bias4.x;
        vb[(size_t)(ocv0+1)*1024 + lg*16 + mrow] = acc[lg][1] + bias4.y;
        vb[(size_t)(ocv0+2)*1024 + lg*16 + mrow] = acc[lg][2] + bias4.z;
        vb[(size_t)(ocv0+3)*1024 + lg*16 + mrow] = acc[lg][3] + bias4.w;
      }
    }
  }
}

// ---------------------------------------------------------------------------
// K3: MX-scaled fp8 MFMA 32x32x64 (unit scales = plain fp8 at 2x rate).
//   R13: best-measured config restored (R9: 2 chains + asm-pinned ds_read
//   pipeline with counted lgkmcnt(8) + sched_barrier + setprio; 62.5us,
//   MfmaUtil 46%) + BT-PAIR MERGE: grid 512 -> 256 (exactly 1 block/CU,
//   ONE dispatch round).  Each block processes 2 key-batches (16 stages);
//   Q fragments loaded once (was twice); rmax flushed to Pm and reset at
//   the bt boundary; the h=1 stage-0 prefetch issues at h=0's last stage,
//   so the mid-block epilogue fold overlaps the next column's staging.
//   Removes the 2nd dispatch round's prologue + drain.
//   Chain-theory post-mortem (R11/R12): 4 chains spills with pipeline,
//   nulls without -> latency is NOT the binding constraint; 46% stands as
//   this structure's ceiling pending an MFMA-shape rewrite (16x16x128
//   would fit 8 chains + pipeline in regs, but its operand lane-layout is
//   undocumented -> not attempted headlessly).
//   Pm layout: [batch(16)][row(16384)].  Grid 256 x 512 threads.
// ---------------------------------------------------------------------------
#define RD8A(FR, CGL)                                                       \
  _Pragma("unroll")                                                         \
  for (int t = 0; t < 8; t++)                                               \
    asm volatile("ds_read_b128 %0, %1 offset:%c2"                           \
                 : "=v"(FR[t]) : "v"(kb), "i"((CGL)*8192 + t*1024));

#define WAITK(N)                                                            \
  asm volatile("s_waitcnt lgkmcnt(" #N ")" ::: "memory");                   \
  __builtin_amdgcn_sched_barrier(0);

#define QK_BURST(FR)                                                        \
  {                                                                         \
    f32x16 a0 = zv, a1 = zv;                                                \
    __builtin_amdgcn_s_setprio(1);                                          \
    _Pragma("unroll")                                                       \
    for (int u = 0; u < 4; u++) {                                           \
      const v8i bu = (v8i){FR[2*u][0],   FR[2*u][1],   FR[2*u][2],   FR[2*u][3], \
                           FR[2*u+1][0], FR[2*u+1][1], FR[2*u+1][2], FR[2*u+1][3]}; \
      a0 = __builtin_amdgcn_mfma_scale_f32_32x32x64_f8f6f4(                 \
          qa[0][u], bu, a0, 0, 0, 0, 0x7F7F7F7F, 0, 0x7F7F7F7F);            \
      a1 = __builtin_amdgcn_mfma_scale_f32_32x32x64_f8f6f4(                 \
          qa[1][u], bu, a1, 0, 0, 0, 0x7F7F7F7F, 0, 0x7F7F7F7F);            \
    }                                                                       \
    __builtin_amdgcn_s_setprio(0);                                          \
    _Pragma("unroll")                                                       \
    for (int i = 0; i < 16; i++) {                                          \
      rmax[0][i] = fmaxf(rmax[0][i], a0[i]);                                \
      rmax[1][i] = fmaxf(rmax[1][i], a1[i]);                                \
    }                                                                       \
  }

__global__ __launch_bounds__(512, 2) void k3_smax(
    const uchar_t* __restrict__ Qf8, const uchar_t* __restrict__ Kf8,
    float* __restrict__ Pm)
{
  __shared__ __align__(16) uchar_t Kl[2][32768];   // 2 x 32 KB

  const int tid = threadIdx.x;
  const int btp = blockIdx.x >> 5;     // bt-pair 0..7 (bts 2*btp, 2*btp+1)
  const int rt = blockIdx.x & 31;      // row-tile (512 rows)
  const int w = tid >> 6, lane = tid & 63;   // w: 0..7
  const int ln31 = lane & 31, half = lane >> 5;

  const int rgb = rt*16 + w*2;         // wave's first row-grp32 (owns 2)
  const int ph = (rt & 1)*4;           // stage-phase rotation (8 stages/bt)

  // prologue: stage 0 of bt=2*btp: 32 chunks; wave w -> c = w*4..w*4+3
  #pragma unroll
  for (int q = 0; q < 4; q++) {
    const int c = w*4 + q;             // cgl = c>>3, kp = c&7
    const int cg = (btp*2)*32 + ph*4 + (c>>3);
    gl_lds16(Kf8 + (((size_t)cg*8 + (c&7))<<10) + lane*16, &Kl[0][c*1024]);
  }

  // Q fragments: 2 rg x 4 u-windows, v8i each (64 VGPR), loaded ONCE for
  // both bt halves (was reloaded per dispatch round before the merge)
  v8i qa[2][4];
  #pragma unroll
  for (int rg = 0; rg < 2; rg++)
    #pragma unroll
    for (int u = 0; u < 4; u++) {
      const int4 p0 = *(const int4*)(Qf8 + (((size_t)(rgb + rg)*8 + 2*u+0)<<10) + lane*16);
      const int4 p1 = *(const int4*)(Qf8 + (((size_t)(rgb + rg)*8 + 2*u+1)<<10) + lane*16);
      qa[rg][u] = (v8i){p0.x, p0.y, p0.z, p0.w, p1.x, p1.y, p1.z, p1.w};
    }

  f32x16 zv;
  #pragma unroll
  for (int i = 0; i < 16; i++) zv[i] = 0.f;
  f32x16 rmax[2];
  #pragma unroll
  for (int rg = 0; rg < 2; rg++)
    #pragma unroll
    for (int i = 0; i < 16; i++) rmax[rg][i] = -3.4e38f;

  const unsigned kb0 = lds_addr(&Kl[0][0]) + lane*16;
  const unsigned kb1 = lds_addr(&Kl[1][0]) + lane*16;

  #pragma unroll 1
  for (int h = 0; h < 2; h++) {        // bt half
    const int bt = btp*2 + h;
    #pragma unroll 1                    // KEEP ROLLED (R3: unroll -> spill)
    for (int s = 0; s < 8; s++) {
      const int sidx = h*8 + s;        // global stage index 0..15
      __syncthreads();                 // stage sidx data visible; vmcnt drained
      if (sidx < 15) {
        const int hn = (sidx + 1) >> 3, sn = (sidx + 1) & 7;
        const int btn = btp*2 + hn;
        const int snp = (sn + ph) & 7;
        #pragma unroll
        for (int q = 0; q < 4; q++) {
          const int c = w*4 + q;
          const int cg = btn*32 + snp*4 + (c>>3);
          gl_lds16(Kf8 + (((size_t)cg*8 + (c&7))<<10) + lane*16,
                   &Kl[(sidx+1)&1][c*1024]);
        }
      }
      const unsigned kb = (sidx & 1) ? kb1 : kb0;

      v4i fA[8], fB[8];
      RD8A(fA, 0)                      // 8 outstanding
      RD8A(fB, 1)                      // 16 outstanding
      WAITK(8)                         // fA ready, fB in flight
      QK_BURST(fA)                     // cgl 0
      RD8A(fA, 2)                      // 16 outstanding (fB + fA')
      WAITK(8)                         // fB ready, fA' in flight
      QK_BURST(fB)                     // cgl 1
      RD8A(fB, 3)                      // 16 outstanding (fA' + fB')
      WAITK(8)                         // fA' ready, fB' in flight
      QK_BURST(fA)                     // cgl 2
      WAITK(0)                         // fB' ready; clean counter for barrier
      QK_BURST(fB)                     // cgl 3
    }

    // per-bt epilogue: per-row max over 32 cols (5 xor-shuffles per half).
    // Runs while the next bt's stage-0 prefetch (issued at sidx==7) flies.
    // C/D: col = lane&31, row = (reg&3) + 8*(reg>>2) + 4*half
    #pragma unroll
    for (int rg = 0; rg < 2; rg++) {
      #pragma unroll
      for (int e = 0; e < 16; e++) {
        float v = rmax[rg][e];
        v = fmaxf(v, __shfl_xor(v, 1));
        v = fmaxf(v, __shfl_xor(v, 2));
        v = fmaxf(v, __shfl_xor(v, 4));
        v = fmaxf(v, __shfl_xor(v, 8));
        v = fmaxf(v, __shfl_xor(v, 16));
        if (ln31 == 0) {
          const int row = rt*512 + w*64 + rg*32 + (e&3) + 8*(e>>2) + 4*half;
          Pm[(size_t)bt*16384 + row] = v;
        }
      }
    }
    if (h == 0) {
      #pragma unroll
      for (int rg = 0; rg < 2; rg++)
        #pragma unroll
        for (int i = 0; i < 16; i++) rmax[rg][i] = -3.4e38f;
    }
  }
}

// ---------------------------------------------------------------------------
// K4: the 32 distinct gate softmaxes, computed ONCE each.
//   Grid 32 = (b 8) x (gidx 4); SW[gidx][b][hw] = softmax weight row.
// ---------------------------------------------------------------------------
__global__ __launch_bounds__(256) void k4_smweights(
    const float* __restrict__ Pm, float* __restrict__ SW)
{
  __shared__ float xw[2][4];
  const int tid = threadIdx.x;
  const int b = blockIdx.x >> 2, gidx = blockIdx.x & 3;
  const int qset = gidx >> 1, side = gidx & 1;

  // logits for hw = tid*4 .. tid*4+3 (coalesced float4 per batch)
  const float4* Pm4 = (const float4*)(Pm + (size_t)side*8*16384 + qset*8192 + b*1024);
  float4 l = {0.f, 0.f, 0.f, 0.f};
  #pragma unroll
  for (int t = 0; t < 8; t++) {
    const float4 p = Pm4[t*4096 + tid];
    l.x += p.x; l.y += p.y; l.z += p.z; l.w += p.w;
  }
  const float sc = 0.125f * 0.0625f;   // mean over 8 batches * 1/sqrt(256)
  l.x *= sc; l.y *= sc; l.z *= sc; l.w *= sc;

  const int w = tid >> 6, lane = tid & 63;
  float m = fmaxf(fmaxf(l.x, l.y), fmaxf(l.z, l.w));
  #pragma unroll
  for (int d = 1; d < 64; d <<= 1) m = fmaxf(m, __shfl_xor(m, d));
  if (lane == 0) xw[0][w] = m;
  __syncthreads();
  m = fmaxf(fmaxf(xw[0][0], xw[0][1]), fmaxf(xw[0][2], xw[0][3]));

  float4 e;
  e.x = expf(l.x - m); e.y = expf(l.y - m);
  e.z = expf(l.z - m); e.w = expf(l.w - m);
  float s = e.x + e.y + e.z + e.w;
  #pragma unroll
  for (int d = 1; d < 64; d <<= 1) s += __shfl_xor(s, d);
  if (lane == 0) xw[1][w] = s;
  __syncthreads();
  s = xw[1][0] + xw[1][1] + xw[1][2] + xw[1][3];
  const float inv = 1.f / s;

  float4 r;
  r.x = e.x*inv; r.y = e.y*inv; r.z = e.z*inv; r.w = e.w*inv;
  *(float4*)&SW[((size_t)(gidx*8 + b) << 10) + (tid << 2)] = r;
}

// ---------------------------------------------------------------------------
// K5: pure streaming gate apply: out[b][ch][hw] = SW[gidx][b][hw] * V + b128.
//   Block = one (b, ch) pair, 256 threads x 1 float4.  Fully coalesced.
//   ch: [x34|a_x4|x43|b_x3]
// ---------------------------------------------------------------------------
__global__ __launch_bounds__(256) void k5_out(
    const float* __restrict__ V, const float* __restrict__ SW,
    const float* __restrict__ b128, float* __restrict__ out)
{
  const int tid = threadIdx.x;
  const int ch = blockIdx.x & 511, b = blockIdx.x >> 9;
  const int blk = ch >> 7, o = ch & 127;
  const int gidx = (blk == 0) ? 2 : (blk == 1) ? 0 : (blk == 2) ? 1 : 3;
  const int src = (blk >= 2) ? 1 : 0;

  const int hw0 = tid << 2;
  const float4 sw = *(const float4*)&SW[((size_t)(gidx*8 + b) << 10) + hw0];
  const float4 v = *(const float4*)&V[((size_t)((src*8 + b)*128 + o) << 10) + hw0];
  const float bias = b128[o];
  float4 r;
  r.x = sw.x*v.x + bias; r.y = sw.y*v.y + bias;
  r.z = sw.z*v.z + bias; r.w = sw.w*v.w + bias;
  *(float4*)&out[((size_t)(b*512 + ch) << 10) + hw0] = r;
}

// ---------------------------------------------------------------------------
extern "C" void kernel_launch(void* const* d_in, const int* in_sizes, int n_in,
                              void* d_out, int out_size, void* d_ws, size_t ws_size,
                              hipStream_t stream)
{
  const float* x4   = (const float*)d_in[0];
  const float* x3   = (const float*)d_in[1];
  const float* wq   = (const float*)d_in[2];
  const float* bq   = (const float*)d_in[3];
  const float* wk   = (const float*)d_in[4];
  const float* bk   = (const float*)d_in[5];
  const float* wv   = (const float*)d_in[6];
  const float* bv   = (const float*)d_in[7];
  const float* w128 = (const float*)d_in[8];
  const float* b128 = (const float*)d_in[9];
  float* out = (float*)d_out;

  char* ws = (char*)d_ws;
  uchar_t*  Qf8 = (uchar_t*)ws;  ws += (size_t)512*8*1024;      // 4 MB
  uchar_t*  Kf8 = (uchar_t*)ws;  ws += (size_t)512*8*1024;      // 4 MB
  float*    V   = (float*)ws;    ws += (size_t)2*8*128*1024*4;  // 8 MB
  float*    Pm  = (float*)ws;    ws += (size_t)16*16384*4;      // 1 MB
  ushort_t* Wf  = (ushort_t*)ws; ws += (size_t)640*256*2;       // 320 KB
  float* bias_all = (float*)ws;  ws += (size_t)640*4;           // 2.5 KB
  float* SW = (float*)ws;                                       // 128 KB

  k1_weights  <<<640,  256, 0, stream>>>(wq, bq, wk, bk, wv, bv, w128, Wf, bias_all);
  k2_features <<<256,  256, 0, stream>>>(x4, x3, Wf, bias_all, Qf8, Kf8, V);
  k3_smax     <<<256,  512, 0, stream>>>(Qf8, Kf8, Pm);
  k4_smweights<<<32,   256, 0, stream>>>(Pm, SW);
  k5_out      <<<4096, 256, 0, stream>>>(V, SW, b128, out);
}

// Round 14
// 173.926 us; speedup vs baseline: 1.2678x; 1.0196x over previous
//
#include <hip/hip_runtime.h>

typedef unsigned short ushort_t;
typedef unsigned char uchar_t;
typedef __attribute__((ext_vector_type(8))) short bf16x8;
typedef __attribute__((ext_vector_type(4))) float f32x4;
typedef __attribute__((ext_vector_type(16))) float f32x16;
typedef __attribute__((ext_vector_type(8))) int v8i;
typedef __attribute__((ext_vector_type(4))) int v4i;

__device__ __forceinline__ unsigned short f2bf(float f) {
  union { float f; unsigned int u; } v; v.f = f;
  unsigned int r = v.u + 0x7FFFu + ((v.u >> 16) & 1u);
  return (unsigned short)(r >> 16);
}

__device__ __forceinline__ float bf2f(unsigned short u) {
  union { unsigned int i; float f; } v; v.i = ((unsigned int)u) << 16;
  return v.f;
}

__device__ __forceinline__ void gl_lds16(const void* gsrc, void* ldst) {
  __builtin_amdgcn_global_load_lds(
      (const __attribute__((address_space(1))) void*)gsrc,
      (__attribute__((address_space(3))) void*)ldst, 16, 0, 0);
}

__device__ __forceinline__ unsigned lds_addr(void* p) {
  return (unsigned)(uintptr_t)(__attribute__((address_space(3))) void*)p;
}

__device__ __forceinline__ int frag_idx(int oc, int ci) {
  return (((oc>>4)*8 + (ci>>5))<<9) + ((((ci>>3)&3)*16 + (oc&15))<<3) + (ci&7);
}

// ---------------------------------------------------------------------------
// K1: fragment-major bf16 weight bank Wf[640][256] (Q=wq, K=wk, V=w128@wv)
//     + bias_all[640].  Blocks 0..511: copy/cast QK.  512..639: V-fold, 1 oc
//     per block.
// ---------------------------------------------------------------------------
__global__ __launch_bounds__(256) void k1_weights(
    const float* __restrict__ wq, const float* __restrict__ bq,
    const float* __restrict__ wk, const float* __restrict__ bk,
    const float* __restrict__ wv, const float* __restrict__ bv,
    const float* __restrict__ w128,
    ushort_t* __restrict__ Wf, float* __restrict__ bias_all)
{
  const int ci = threadIdx.x;
  const int oc = blockIdx.x;
  if (oc < 512) {
    const float v = (oc < 256) ? wq[oc*256 + ci] : wk[(oc-256)*256 + ci];
    Wf[frag_idx(oc, ci)] = f2bf(v);
    if (ci == 0) bias_all[oc] = (oc < 256) ? bq[oc] : bk[oc-256];
  } else {
    const int o = oc - 512;
    const float* wr = w128 + (size_t)o*256;
    float a = 0.f;
    for (int co = 0; co < 256; co++) a += wr[co] * wv[co*256 + ci];
    Wf[frag_idx(oc, ci)] = f2bf(a);
    if (ci == 0) {
      float s = 0.f;
      for (int co = 0; co < 256; co++) s += wr[co] * bv[co];
      bias_all[oc] = s;
    }
  }
}

// ---------------------------------------------------------------------------
// K2: MFMA feature GEMM (bf16 16x16x32 internally).  Grid (256,1): one block
//   per 64-px tile runs ALL 10 output tiles (ot).
//   ot 0..3 -> Qf8, 4..7 -> Kf8 (fp8 e4m3 chunks), ot 8..9 -> V fp32.
//   R10: Af B-fragments hoisted to 128 VGPR once per wave; x staged once.
//   R14: OCCUPANCY FIX -- k2 ran at 1 wave/SIMD (105 KB LDS -> 1 block/CU),
//   so every Wf-load wait / LDS read / barrier was fully exposed.
//   (a) Af aliased onto Wl[1]: Af is consumed into bb registers before the
//       ot loop first writes Wl[1] (extra barrier after bb reads makes the
//       hand-off explicit).  LDS 105 -> 73 KB -> 2 blocks/CU, 2 waves/SIMD.
//   (b) Lt-phase barriers: __syncthreads (drains vmcnt(0), killing the Wf
//       prefetch every ot) -> s_waitcnt lgkmcnt(0) + raw s_barrier (Lt deps
//       are DS-only; uniform arrival, all threads same path).  The loop-top
//       vmcnt(8) stays the sole Wl gate: at that point the 8 newest loads
//       are the just-issued next-ot set, so <=8 outstanding == previous
//       ot's loads complete -- correct with or without barrier drains.
// ---------------------------------------------------------------------------
#define BAR_DS                                                              \
  asm volatile("s_waitcnt lgkmcnt(0)" ::: "memory");                        \
  __builtin_amdgcn_s_barrier();

__global__ __launch_bounds__(256) void k2_features(
    const float* __restrict__ x4, const float* __restrict__ x3,
    const ushort_t* __restrict__ Wf, const float* __restrict__ bias_all,
    uchar_t* __restrict__ Qf8, uchar_t* __restrict__ Kf8, float* __restrict__ V)
{
  __shared__ ushort_t Wl[2][32*512];   // 2 x 32 KB; Wl[1] doubles as Af
  __shared__ ushort_t Lt[64*72];       // repack buffer (bf16), ~9 KB

  const int tid = threadIdx.x;
  const int w = tid >> 6, lane = tid & 63;
  const int mrow = lane & 15, quad = lane >> 4;
  const int ln31 = lane & 31, half = lane >> 5;

  const int px0 = blockIdx.x * 64;
  const int src = px0 >> 13, b = (px0 >> 10) & 7, hw0 = px0 & 1023;
  const float* xp = (src ? x3 : x4) + (size_t)b*262144;

  // prologue: W-frags for ot=0 -> Wl[0]
  for (int kb = 0; kb < 8; kb++)
    gl_lds16(Wf + ((size_t)(w*8 + kb)<<9) + lane*8,
             &Wl[0][(w*8+kb)*512]);

  {  // stage x into Af (= Wl[1])
    const int hw = hw0 + w*16 + mrow;
    for (int kb = 0; kb < 8; kb++) {
      const int ch0 = kb*32 + quad*8;
      bf16x8 pk;
      #pragma unroll
      for (int j = 0; j < 8; j++)
        ((ushort_t*)&pk)[j] = f2bf(xp[(size_t)(ch0 + j)*1024 + hw]);
      *(bf16x8*)&Wl[1][(w*8 + kb)*512 + lane*8] = pk;
    }
  }
  __syncthreads();   // Wl[0] gl_lds + Af ds_writes complete, block-wide

  // hoist B-fragments (ot-invariant) into registers: 32 x bf16x8 = 128 VGPR
  bf16x8 bb[4][8];
  #pragma unroll
  for (int lg = 0; lg < 4; lg++)
    #pragma unroll
    for (int kb = 0; kb < 8; kb++)
      bb[lg][kb] = *(const bf16x8*)&Wl[1][(lg*8 + kb)*512 + lane*8];
  __syncthreads();   // all bb reads done before ot=0 prefetch overwrites Wl[1]

  for (int ot = 0; ot < 10; ot++) {
    const int cbuf = ot & 1, nbuf = cbuf ^ 1;
    if (ot + 1 < 10) {
      for (int kb = 0; kb < 8; kb++)
        gl_lds16(Wf + ((size_t)(((ot+1)*4 + w)*8 + kb)<<9) + lane*8,
                 &Wl[nbuf][(w*8+kb)*512]);
      asm volatile("s_waitcnt vmcnt(8)" ::: "memory");
    } else {
      asm volatile("s_waitcnt vmcnt(0)" ::: "memory");
    }

    f32x4 acc[4];
    #pragma unroll
    for (int lg = 0; lg < 4; lg++) acc[lg] = (f32x4){0.f,0.f,0.f,0.f};
    #pragma unroll
    for (int kb = 0; kb < 8; kb++) {
      const bf16x8 a = *(const bf16x8*)&Wl[cbuf][(w*8 + kb)*512 + lane*8];
      #pragma unroll
      for (int lg = 0; lg < 4; lg++)
        acc[lg] = __builtin_amdgcn_mfma_f32_16x16x32_bf16(a, bb[lg][kb], acc[lg], 0, 0, 0);
    }
    const int ocl = w*16 + quad*4;
    const float4 bias4 = *(const float4*)&bias_all[ot*64 + ocl];

    if (ot < 8) {
      BAR_DS   // prev ot's Lt reads complete (DS-only; keeps prefetch alive)
      #pragma unroll
      for (int lg = 0; lg < 4; lg++) {
        const int px = lg*16 + mrow;
        ushort4 pk;
        pk.x = f2bf(acc[lg][0] + bias4.x);
        pk.y = f2bf(acc[lg][1] + bias4.y);
        pk.z = f2bf(acc[lg][2] + bias4.z);
        pk.w = f2bf(acc[lg][3] + bias4.w);
        *(ushort4*)&Lt[px*72 + ocl] = pk;
      }
      BAR_DS   // Lt writes visible block-wide
      // emit one fp8 chunk per wave: wave w -> g = w>>1, e = w&1
      const int g = w >> 1, e = w & 1;
      const int row = g*32 + ln31;
      const ushort_t* lp = &Lt[row*72 + e*32 + half*8];
      float fl[8], fh[8];
      #pragma unroll
      for (int j = 0; j < 8; j++) { fl[j] = bf2f(lp[j]); fh[j] = bf2f(lp[16+j]); }
      int w0 = __builtin_amdgcn_cvt_pk_fp8_f32(fl[0], fl[1], 0, 0);
      w0     = __builtin_amdgcn_cvt_pk_fp8_f32(fl[2], fl[3], w0, 1);
      int w1 = __builtin_amdgcn_cvt_pk_fp8_f32(fl[4], fl[5], 0, 0);
      w1     = __builtin_amdgcn_cvt_pk_fp8_f32(fl[6], fl[7], w1, 1);
      int w2 = __builtin_amdgcn_cvt_pk_fp8_f32(fh[0], fh[1], 0, 0);
      w2     = __builtin_amdgcn_cvt_pk_fp8_f32(fh[2], fh[3], w2, 1);
      int w3 = __builtin_amdgcn_cvt_pk_fp8_f32(fh[4], fh[5], 0, 0);
      w3     = __builtin_amdgcn_cvt_pk_fp8_f32(fh[6], fh[7], w3, 1);
      uchar_t* dst = (ot < 4) ? Qf8 : Kf8;
      const size_t chunk = (size_t)((px0>>5) + g)*8 + (ot&3)*2 + e;
      int4 pk4; pk4.x = w0; pk4.y = w1; pk4.z = w2; pk4.w = w3;
      *(int4*)(dst + (chunk<<10) + lane*16) = pk4;
    } else {
      const int ocv0 = (ot-8)*64 + ocl;
      float* vb = V + (((size_t)(src*8 + b)*128) << 10) + hw0;
      #pragma unroll
      for (int lg = 0; lg < 4; lg++) {
        vb[(size_t)(ocv0+0)*1024 + lg*16 + mrow] = acc[lg][0] + bias4.x;
        vb[(size_t)(ocv0+1)*1024 + lg*16 + mrow] = acc[lg][1] + bias4.y;
        vb[(size_t)(ocv0+2)*1024 + lg*16 + mrow] = acc[lg][2] + bias4.z;
        vb[(size_t)(ocv0+3)*1024 + lg*16 + mrow] = acc[lg][3] + bias4.w;
      }
    }
  }
}

// ---------------------------------------------------------------------------
// K3: MX-scaled fp8 MFMA 32x32x64 (unit scales = plain fp8 at 2x rate).
//   R14: REVERTED to the R9/R10 grid-512 config (best measured: 62.5us,
//   MfmaUtil 46%, stable across 5 runs).  R13's bt-pair merge was null on
//   the healthy path (62.7) and produced a 41.9ms outlier dispatch -- the
//   2nd sync-structure change to hit a scheduler pathology (R6 was 1st).
//   Structure: 8 waves x 64 rows (2 rg32), 2 waves/SIMD, LDS dbuf 2x32KB,
//   __syncthreads stage loop ROLLED, asm-pinned ds_read pipeline with
//   counted lgkmcnt(8) + sched_barrier(0), setprio around bursts.
//   Lever post-mortem: occupancy(R1-3) +38%, asm pipeline(R8) +2%,
//   setprio(R9) +2%; refuted: spill-free 4-chain(R12), direct-L2(R5),
//   8-phase(R6), bt-merge(R13).  46% = this structure's ceiling.
//   Pm layout: [batch(16)][row(16384)].  Grid 512 x 512 threads.
// ---------------------------------------------------------------------------
#define RD8A(FR, CGL)                                                       \
  _Pragma("unroll")                                                         \
  for (int t = 0; t < 8; t++)                                               \
    asm volatile("ds_read_b128 %0, %1 offset:%c2"                           \
                 : "=v"(FR[t]) : "v"(kb), "i"((CGL)*8192 + t*1024));

#define WAITK(N)                                                            \
  asm volatile("s_waitcnt lgkmcnt(" #N ")" ::: "memory");                   \
  __builtin_amdgcn_sched_barrier(0);

#define QK_BURST(FR)                                                        \
  {                                                                         \
    f32x16 a0 = zv, a1 = zv;                                                \
    __builtin_amdgcn_s_setprio(1);                                          \
    _Pragma("unroll")                                                       \
    for (int u = 0; u < 4; u++) {                                           \
      const v8i bu = (v8i){FR[2*u][0],   FR[2*u][1],   FR[2*u][2],   FR[2*u][3], \
                           FR[2*u+1][0], FR[2*u+1][1], FR[2*u+1][2], FR[2*u+1][3]}; \
      a0 = __builtin_amdgcn_mfma_scale_f32_32x32x64_f8f6f4(                 \
          qa[0][u], bu, a0, 0, 0, 0, 0x7F7F7F7F, 0, 0x7F7F7F7F);            \
      a1 = __builtin_amdgcn_mfma_scale_f32_32x32x64_f8f6f4(                 \
          qa[1][u], bu, a1, 0, 0, 0, 0x7F7F7F7F, 0, 0x7F7F7F7F);            \
    }                                                                       \
    __builtin_amdgcn_s_setprio(0);                                          \
    _Pragma("unroll")                                                       \
    for (int i = 0; i < 16; i++) {                                          \
      rmax[0][i] = fmaxf(rmax[0][i], a0[i]);                                \
      rmax[1][i] = fmaxf(rmax[1][i], a1[i]);                                \
    }                                                                       \
  }

__global__ __launch_bounds__(512, 2) void k3_smax(
    const uchar_t* __restrict__ Qf8, const uchar_t* __restrict__ Kf8,
    float* __restrict__ Pm)
{
  __shared__ __align__(16) uchar_t Kl[2][32768];   // 2 x 32 KB

  const int tid = threadIdx.x;
  const int bt = blockIdx.x >> 5;      // key-batch 0..15
  const int rt = blockIdx.x & 31;      // row-tile (512 rows)
  const int w = tid >> 6, lane = tid & 63;   // w: 0..7
  const int ln31 = lane & 31, half = lane >> 5;

  const int rgb = rt*16 + w*2;         // wave's first row-grp32 (owns 2)
  const int ph = (blockIdx.x & 1)*4;   // stage-phase rotation (8 stages)

  // prologue: stage s=0: 32 chunks (4 cgl x 8 kp); wave w -> c = w*4..w*4+3
  #pragma unroll
  for (int q = 0; q < 4; q++) {
    const int c = w*4 + q;             // cgl = c>>3, kp = c&7
    const int cg = bt*32 + ph*4 + (c>>3);
    gl_lds16(Kf8 + (((size_t)cg*8 + (c&7))<<10) + lane*16, &Kl[0][c*1024]);
  }

  // Q fragments: 2 rg x 4 u-windows, v8i each (64 VGPR), resident whole kernel
  v8i qa[2][4];
  #pragma unroll
  for (int rg = 0; rg < 2; rg++)
    #pragma unroll
    for (int u = 0; u < 4; u++) {
      const int4 p0 = *(const int4*)(Qf8 + (((size_t)(rgb + rg)*8 + 2*u+0)<<10) + lane*16);
      const int4 p1 = *(const int4*)(Qf8 + (((size_t)(rgb + rg)*8 + 2*u+1)<<10) + lane*16);
      qa[rg][u] = (v8i){p0.x, p0.y, p0.z, p0.w, p1.x, p1.y, p1.z, p1.w};
    }

  f32x16 zv;
  #pragma unroll
  for (int i = 0; i < 16; i++) zv[i] = 0.f;
  f32x16 rmax[2];
  #pragma unroll
  for (int rg = 0; rg < 2; rg++)
    #pragma unroll
    for (int i = 0; i < 16; i++) rmax[rg][i] = -3.4e38f;

  const unsigned kb0 = lds_addr(&Kl[0][0]) + lane*16;
  const unsigned kb1 = lds_addr(&Kl[1][0]) + lane*16;

  #pragma unroll 1                      // KEEP ROLLED (R3: unroll -> spill)
  for (int s = 0; s < 8; s++) {
    __syncthreads();                   // stage s data visible; vmcnt drained
    if (s < 7) {
      const int sn = (s + 1 + ph) & 7;
      #pragma unroll
      for (int q = 0; q < 4; q++) {
        const int c = w*4 + q;
        const int cg = bt*32 + sn*4 + (c>>3);
        gl_lds16(Kf8 + (((size_t)cg*8 + (c&7))<<10) + lane*16,
                 &Kl[(s+1)&1][c*1024]);
      }
    }
    const unsigned kb = (s & 1) ? kb1 : kb0;

    v4i fA[8], fB[8];
    RD8A(fA, 0)                        // 8 outstanding
    RD8A(fB, 1)                        // 16 outstanding
    WAITK(8)                           // fA ready, fB in flight
    QK_BURST(fA)                       // cgl 0
    RD8A(fA, 2)                        // 16 outstanding (fB + fA')
    WAITK(8)                           // fB ready, fA' in flight
    QK_BURST(fB)                       // cgl 1
    RD8A(fB, 3)                        // 16 outstanding (fA' + fB')
    WAITK(8)                           // fA' ready, fB' in flight
    QK_BURST(fA)                       // cgl 2
    WAITK(0)                           // fB' ready; clean counter for barrier
    QK_BURST(fB)                       // cgl 3
  }

  // epilogue: per-row max over 32 cols (5 xor-shuffles in each 32-lane half)
  // C/D: col = lane&31, row = (reg&3) + 8*(reg>>2) + 4*half (shape-determined)
  #pragma unroll
  for (int rg = 0; rg < 2; rg++) {
    #pragma unroll
    for (int e = 0; e < 16; e++) {
      float v = rmax[rg][e];
      v = fmaxf(v, __shfl_xor(v, 1));
      v = fmaxf(v, __shfl_xor(v, 2));
      v = fmaxf(v, __shfl_xor(v, 4));
      v = fmaxf(v, __shfl_xor(v, 8));
      v = fmaxf(v, __shfl_xor(v, 16));
      if (ln31 == 0) {
        const int row = rt*512 + w*64 + rg*32 + (e&3) + 8*(e>>2) + 4*half;
        Pm[(size_t)bt*16384 + row] = v;
      }
    }
  }
}

// ---------------------------------------------------------------------------
// K4: the 32 distinct gate softmaxes, computed ONCE each.
//   Grid 32 = (b 8) x (gidx 4); SW[gidx][b][hw] = softmax weight row.
// ---------------------------------------------------------------------------
__global__ __launch_bounds__(256) void k4_smweights(
    const float* __restrict__ Pm, float* __restrict__ SW)
{
  __shared__ float xw[2][4];
  const int tid = threadIdx.x;
  const int b = blockIdx.x >> 2, gidx = blockIdx.x & 3;
  const int qset = gidx >> 1, side = gidx & 1;

  // logits for hw = tid*4 .. tid*4+3 (coalesced float4 per batch)
  const float4* Pm4 = (const float4*)(Pm + (size_t)side*8*16384 + qset*8192 + b*1024);
  float4 l = {0.f, 0.f, 0.f, 0.f};
  #pragma unroll
  for (int t = 0; t < 8; t++) {
    const float4 p = Pm4[t*4096 + tid];
    l.x += p.x; l.y += p.y; l.z += p.z; l.w += p.w;
  }
  const float sc = 0.125f * 0.0625f;   // mean over 8 batches * 1/sqrt(256)
  l.x *= sc; l.y *= sc; l.z *= sc; l.w *= sc;

  const int w = tid >> 6, lane = tid & 63;
  float m = fmaxf(fmaxf(l.x, l.y), fmaxf(l.z, l.w));
  #pragma unroll
  for (int d = 1; d < 64; d <<= 1) m = fmaxf(m, __shfl_xor(m, d));
  if (lane == 0) xw[0][w] = m;
  __syncthreads();
  m = fmaxf(fmaxf(xw[0][0], xw[0][1]), fmaxf(xw[0][2], xw[0][3]));

  float4 e;
  e.x = expf(l.x - m); e.y = expf(l.y - m);
  e.z = expf(l.z - m); e.w = expf(l.w - m);
  float s = e.x + e.y + e.z + e.w;
  #pragma unroll
  for (int d = 1; d < 64; d <<= 1) s += __shfl_xor(s, d);
  if (lane == 0) xw[1][w] = s;
  __syncthreads();
  s = xw[1][0] + xw[1][1] + xw[1][2] + xw[1][3];
  const float inv = 1.f / s;

  float4 r;
  r.x = e.x*inv; r.y = e.y*inv; r.z = e.z*inv; r.w = e.w*inv;
  *(float4*)&SW[((size_t)(gidx*8 + b) << 10) + (tid << 2)] = r;
}

// ---------------------------------------------------------------------------
// K5: pure streaming gate apply: out[b][ch][hw] = SW[gidx][b][hw] * V + b128.
//   Block = one (b, ch) pair, 256 threads x 1 float4.  Fully coalesced.
//   ch: [x34|a_x4|x43|b_x3]
// ---------------------------------------------------------------------------
__global__ __launch_bounds__(256) void k5_out(
    const float* __restrict__ V, const float* __restrict__ SW,
    const float* __restrict__ b128, float* __restrict__ out)
{
  const int tid = threadIdx.x;
  const int ch = blockIdx.x & 511, b = blockIdx.x >> 9;
  const int blk = ch >> 7, o = ch & 127;
  const int gidx = (blk == 0) ? 2 : (blk == 1) ? 0 : (blk == 2) ? 1 : 3;
  const int src = (blk >= 2) ? 1 : 0;

  const int hw0 = tid << 2;
  const float4 sw = *(const float4*)&SW[((size_t)(gidx*8 + b) << 10) + hw0];
  const float4 v = *(const float4*)&V[((size_t)((src*8 + b)*128 + o) << 10) + hw0];
  const float bias = b128[o];
  float4 r;
  r.x = sw.x*v.x + bias; r.y = sw.y*v.y + bias;
  r.z = sw.z*v.z + bias; r.w = sw.w*v.w + bias;
  *(float4*)&out[((size_t)(b*512 + ch) << 10) + hw0] = r;
}

// ---------------------------------------------------------------------------
extern "C" void kernel_launch(void* const* d_in, const int* in_sizes, int n_in,
                              void* d_out, int out_size, void* d_ws, size_t ws_size,
                              hipStream_t stream)
{
  const float* x4   = (const float*)d_in[0];
  const float* x3   = (const float*)d_in[1];
  const float* wq   = (const float*)d_in[2];
  const float* bq   = (const float*)d_in[3];
  const float* wk   = (const float*)d_in[4];
  const float* bk   = (const float*)d_in[5];
  const float* wv   = (const float*)d_in[6];
  const float* bv   = (const float*)d_in[7];
  const float* w128 = (const float*)d_in[8];
  const float* b128 = (const float*)d_in[9];
  float* out = (float*)d_out;

  char* ws = (char*)d_ws;
  uchar_t*  Qf8 = (uchar_t*)ws;  ws += (size_t)512*8*1024;      // 4 MB
  uchar_t*  Kf8 = (uchar_t*)ws;  ws += (size_t)512*8*1024;      // 4 MB
  float*    V   = (float*)ws;    ws += (size_t)2*8*128*1024*4;  // 8 MB
  float*    Pm  = (float*)ws;    ws += (size_t)16*16384*4;      // 1 MB
  ushort_t* Wf  = (ushort_t*)ws; ws += (size_t)640*256*2;       // 320 KB
  float* bias_all = (float*)ws;  ws += (size_t)640*4;           // 2.5 KB
  float* SW = (float*)ws;                                       // 128 KB

  k1_weights  <<<640,  256, 0, stream>>>(wq, bq, wk, bk, wv, bv, w128, Wf, bias_all);
  k2_features <<<256,  256, 0, stream>>>(x4, x3, Wf, bias_all, Qf8, Kf8, V);
  k3_smax     <<<512,  512, 0, stream>>>(Qf8, Kf8, Pm);
  k4_smweights<<<32,   256, 0, stream>>>(Pm, SW);
  k5_out      <<<4096, 256, 0, stream>>>(V, SW, b128, out);
}